// Round 21
// baseline (309.786 us; speedup 1.0000x reference)
//
#include <hip/hip_runtime.h>
#include <hip/hip_bf16.h>

#define SEQ 4096
#define BATCH 2
#define NH 16
#define DH 64
#define DM 1024

typedef float f32x4 __attribute__((ext_vector_type(4)));
typedef __bf16 bf16x8 __attribute__((ext_vector_type(8)));
typedef __bf16 bf16x4 __attribute__((ext_vector_type(4)));

#define MFMA16(a, b, c) __builtin_amdgcn_mfma_f32_16x16x32_bf16((a), (b), (c), 0, 0, 0)

// Round-21: LDS diet to EXACTLY 40KB -> 4 blocks/CU (round-20 showed the
// KV-split was LDS-capped at 2 blocks/CU: 64.5KB). Changes:
//  - lp 32KB -> 8KB: PV moved inside the per-i loop (per-wave 16x64 P
//    sub-tile; same-wave write->read is lgkm-ordered, no barrier).
//  - lm eliminated: mask in regs, msv via 16 __shfl/tile.
//  - lk/lv stay double-buffered -> single barrier per tile kept.
// 16384+16384+8192 = 40960 B. VGPR ~124 <= 128 -> 4 waves/SIMD possible.
// Keeps: KV-split x2 (linear combine, fixed max M=16), raw v_exp_f32,
// swizzled LDS, MFMA-ones row-sum, reg-staged double buffer.

typedef const __attribute__((address_space(1))) unsigned int* gas_t;
typedef __attribute__((address_space(3))) unsigned int* las_t;
__device__ __forceinline__ void gload16(const __bf16* g, __bf16* l) {
    __builtin_amdgcn_global_load_lds((gas_t)(const void*)g, (las_t)(void*)l, 16, 0, 0);
}

// ---------------------------------------------------------------------------
// One-shot fp32 -> bf16 convert for GEMM operands (memory-bound, ~20us).
// ---------------------------------------------------------------------------
__global__ __launch_bounds__(256) void cvt7_kernel(
    const float* __restrict__ a0, const float* __restrict__ a1, const float* __restrict__ a2,
    const float* __restrict__ a3, const float* __restrict__ a4, const float* __restrict__ a5,
    const float* __restrict__ a6,
    __bf16* __restrict__ b0, __bf16* __restrict__ b1, __bf16* __restrict__ b2,
    __bf16* __restrict__ b3, __bf16* __restrict__ b4, __bf16* __restrict__ b5,
    __bf16* __restrict__ b6, int nbig, int nw)
{
    const int y = blockIdx.y;
    const float* s; __bf16* d; int n;
    switch (y) {
        case 0: s = a0; d = b0; n = nbig; break;
        case 1: s = a1; d = b1; n = nbig; break;
        case 2: s = a2; d = b2; n = nbig; break;
        case 3: s = a3; d = b3; n = nw;   break;
        case 4: s = a4; d = b4; n = nw;   break;
        case 5: s = a5; d = b5; n = nw;   break;
        default: s = a6; d = b6; n = nw;  break;
    }
    const int idx = (blockIdx.x * 256 + threadIdx.x) * 8;
    if (idx >= n) return;
    const float4 v0 = *(const float4*)(s + idx);
    const float4 v1 = *(const float4*)(s + idx + 4);
    bf16x8 o;
    o[0] = (__bf16)v0.x; o[1] = (__bf16)v0.y; o[2] = (__bf16)v0.z; o[3] = (__bf16)v0.w;
    o[4] = (__bf16)v1.x; o[5] = (__bf16)v1.y; o[6] = (__bf16)v1.z; o[7] = (__bf16)v1.w;
    *(bf16x8*)(d + idx) = o;
}

// ---------------------------------------------------------------------------
// QKV projection, bf16, gload_lds staging: C = X @ W^T + bias (NT, 128x128)
// z=0 -> q PRE-SCALED by 1/sqrt(64)*log2e; z=1 -> k; z=2 -> v^T (B,H,64,S)
// ---------------------------------------------------------------------------
__global__ __launch_bounds__(256) void qkv_proj_kernel(
    const __bf16* __restrict__ Qb, const __bf16* __restrict__ Kb, const __bf16* __restrict__ Vb,
    const __bf16* __restrict__ Wq, const __bf16* __restrict__ Wk, const __bf16* __restrict__ Wv,
    const float* __restrict__ bq, const float* __restrict__ bk, const float* __restrict__ bv,
    __bf16* __restrict__ qo, __bf16* __restrict__ ko, __bf16* __restrict__ vto)
{
    const int z = blockIdx.z;
    const __bf16* __restrict__ X    = (z == 0) ? Qb : (z == 1) ? Kb : Vb;
    const __bf16* __restrict__ W    = (z == 0) ? Wq : (z == 1) ? Wk : Wv;
    const float*  __restrict__ bias = (z == 0) ? bq : (z == 1) ? bk : bv;

    __shared__ __bf16 la[128 * 64];
    __shared__ __bf16 lb[128 * 64];

    const int t = threadIdx.x;
    const int lane = t & 63;
    const int w = t >> 6;
    const int wr = w >> 1, wc = w & 1;
    const int m0 = blockIdx.y * 128;
    const int n0 = blockIdx.x * 128;
    const int col_l = lane & 15;
    const int row_l = (lane >> 4) * 4;
    const int g = lane >> 4;
    const int swz = col_l & 7;              // read-side swizzle key (row&7)

    const int lrow = lane >> 3;             // staging: 8 lanes/row, 16B each
    const int lchk = (lane & 7) ^ lrow;     // inverse-swizzle source chunk
    const __bf16* aG = X + (size_t)(m0 + w * 32 + lrow) * DM + lchk * 8;
    const __bf16* bG = W + (size_t)(n0 + w * 32 + lrow) * DM + lchk * 8;

    f32x4 acc[4][4];
#pragma unroll
    for (int i = 0; i < 4; ++i)
#pragma unroll
        for (int j = 0; j < 4; ++j) acc[i][j] = f32x4{0.f, 0.f, 0.f, 0.f};

    for (int k0 = 0; k0 < DM; k0 += 64) {
        __syncthreads();                    // prior compute done reading la/lb
#pragma unroll
        for (int i = 0; i < 4; ++i) {
            gload16(aG + k0 + (size_t)(i * 8) * DM, &la[(w * 32 + i * 8) * 64]);
            gload16(bG + k0 + (size_t)(i * 8) * DM, &lb[(w * 32 + i * 8) * 64]);
        }
        __syncthreads();                    // vmcnt drained: tiles resident
#pragma unroll
        for (int kk = 0; kk < 2; ++kk) {
            bf16x8 afr[4], bfr[4];
            const int rslot = ((kk * 4 + g) ^ swz) * 8;
#pragma unroll
            for (int i = 0; i < 4; ++i)
                afr[i] = *(const bf16x8*)&la[(wr * 64 + i * 16 + col_l) * 64 + rslot];
#pragma unroll
            for (int j = 0; j < 4; ++j)
                bfr[j] = *(const bf16x8*)&lb[(wc * 64 + j * 16 + col_l) * 64 + rslot];
#pragma unroll
            for (int i = 0; i < 4; ++i)
#pragma unroll
                for (int j = 0; j < 4; ++j)
                    acc[i][j] = MFMA16(afr[i], bfr[j], acc[i][j]);
        }
    }

    const float qscale = (z == 0) ? 0.125f * 1.44269504f : 1.0f;

    // epilogue: C/D layout col=lane&15, row=(lane>>4)*4+reg  [m89]
#pragma unroll
    for (int i = 0; i < 4; ++i) {
#pragma unroll
        for (int j = 0; j < 4; ++j) {
            const int n = n0 + wc * 64 + j * 16 + col_l;
            const float bb = bias[n];
            const int hh = n >> 6, d = n & 63;
            const int mbase = m0 + wr * 64 + i * 16 + row_l;
            const int b = mbase >> 12;
            const int s = mbase & 4095;
            if (z == 2) {
                bf16x4 pk;
#pragma unroll
                for (int r = 0; r < 4; ++r) pk[r] = (__bf16)(acc[i][j][r] + bb);
                *(bf16x4*)&vto[((size_t)((b * NH + hh) * DH + d)) * SEQ + s] = pk;
            } else {
                __bf16* op = (z == 0) ? qo : ko;
#pragma unroll
                for (int r = 0; r < 4; ++r)
                    op[((size_t)((b * NH + hh) * SEQ + s + r)) * DH + d] =
                        (__bf16)((acc[i][j][r] + bb) * qscale);
            }
        }
    }
}

// ---------------------------------------------------------------------------
// Flash attention, round-21: 40KB LDS (4 blocks/CU), per-i PV, mask-in-regs.
// KV-split (blockIdx.z); writes UNNORMALIZED partial O (bf16) + f32 csum.
// ---------------------------------------------------------------------------
__global__ __launch_bounds__(256, 2) void attn_kernel(
    const __bf16* __restrict__ qg, const __bf16* __restrict__ kg,
    const __bf16* __restrict__ vtg, const float* __restrict__ maskg,
    __bf16* __restrict__ pog, float* __restrict__ cog)
{
    const int bh = blockIdx.y;
    const int b = bh >> 4;
    const int q0 = blockIdx.x * 256;
    const int zkv = blockIdx.z;
    const int kv0 = zkv * (SEQ / 2);
    const int t = threadIdx.x;
    const int lane = t & 63;
    const int w = t >> 6;
    const int col_l = lane & 15;
    const int g = lane >> 4;          // 4 lane-groups; key sub-slot g*4+r
    const int swz = col_l & 7;        // read-side swizzle key

    __shared__ __bf16 lk[2][64 * 64];   // keys x d
    __shared__ __bf16 lv[2][64 * 64];   // V transposed: d x keys
    __shared__ __bf16 lp[4][16 * 64];   // per-wave CURRENT-i P tile (16 q x 64 k)
    // total LDS = 16384 + 16384 + 8192 = 40960 B exactly -> 4 blocks/CU

    const __bf16* qbase = qg + (size_t)bh * SEQ * DH;
    const __bf16* kbase = kg + (size_t)bh * SEQ * DH;
    const __bf16* vbase = vtg + (size_t)bh * DH * SEQ;

    // Q resident in registers (pre-scaled by 1/sqrt(d)*log2e)
    bf16x8 qf[4][2];
#pragma unroll
    for (int i = 0; i < 4; ++i)
#pragma unroll
        for (int kk = 0; kk < 2; ++kk)
            qf[i][kk] = *(const bf16x8*)&qbase[(size_t)(q0 + w * 64 + i * 16 + col_l) * DH +
                                              kk * 32 + g * 8];

    bf16x8 ones;
#pragma unroll
    for (int e = 0; e < 8; ++e) ones[e] = (__bf16)1.0f;

    f32x4 oaccT[4][4], csum[4];
#pragma unroll
    for (int jd = 0; jd < 4; ++jd)
#pragma unroll
        for (int i = 0; i < 4; ++i) oaccT[jd][i] = f32x4{0.f, 0.f, 0.f, 0.f};
#pragma unroll
    for (int i = 0; i < 4; ++i) csum[i] = f32x4{0.f, 0.f, 0.f, 0.f};

    const int srow = t >> 2;          // staging: 4 threads/row, 32B each
    const int wkey = srow & 7;
    const int ss0 = ((t & 3) * 2) ^ wkey;        // swizzled slot, first 16B
    const int ss1 = ((t & 3) * 2 + 1) ^ wkey;    // swizzled slot, second 16B

    // staged registers for the in-flight tile (+ per-wave mask lane regs)
    bf16x8 sk0, sk1, sv0, sv1;
    float mcur, mnxt;

    auto LOADT = [&](int j0) {
        const bf16x8* ksrc = (const bf16x8*)(kbase + (size_t)j0 * DH);
        sk0 = ksrc[t * 2];
        sk1 = ksrc[t * 2 + 1];
        const __bf16* vsrc = vbase + (size_t)srow * SEQ + j0 + (t & 3) * 16;
        sv0 = *(const bf16x8*)vsrc;
        sv1 = *(const bf16x8*)(vsrc + 8);
        mnxt = maskg[b * SEQ + j0 + lane];   // every wave: lane l <-> key j0+l
    };
    auto WRITET = [&](int buf) {
        *(bf16x8*)&lk[buf][srow * 64 + ss0 * 8] = sk0;
        *(bf16x8*)&lk[buf][srow * 64 + ss1 * 8] = sk1;
        *(bf16x8*)&lv[buf][srow * 64 + ss0 * 8] = sv0;
        *(bf16x8*)&lv[buf][srow * 64 + ss1 * 8] = sv1;
    };

    const int NT = (SEQ / 2) / 64;   // 32 tiles per half
    LOADT(kv0);
    WRITET(0);
    mcur = mnxt;
    __syncthreads();

    for (int tt = 0; tt < NT; ++tt) {
        const int cur = tt & 1;
        const bool more = (tt + 1 < NT);
        if (more) LOADT(kv0 + (tt + 1) * 64);   // in flight during compute

        // mask bias from regs: msv[j][r] for key j*16+g*4+r (16 shfl/tile)
        f32x4 msv[4];
#pragma unroll
        for (int j = 0; j < 4; ++j)
#pragma unroll
            for (int r = 0; r < 4; ++r) {
                const float mv = __shfl(mcur, j * 16 + g * 4 + r, 64);
                msv[j][r] = (mv == 0.0f) ? -1e9f : -16.0f;
            }

        // K frags hoisted once per tile (A-operand: m=key block j, row=col_l)
        bf16x8 kf[4][2];
#pragma unroll
        for (int j = 0; j < 4; ++j)
#pragma unroll
            for (int kk = 0; kk < 2; ++kk)
                kf[j][kk] = *(const bf16x8*)&lk[cur][(j * 16 + col_l) * 64 +
                                                    ((kk * 4 + g) ^ swz) * 8];

        // Per q-block i: QK^T -> exp2 -> lp (16x64) -> PV immediately.
#pragma unroll
        for (int i = 0; i < 4; ++i) {
            f32x4 sacc[4];
#pragma unroll
            for (int j = 0; j < 4; ++j) sacc[j] = msv[j];
#pragma unroll
            for (int kk = 0; kk < 2; ++kk)
#pragma unroll
                for (int j = 0; j < 4; ++j)
                    sacc[j] = MFMA16(kf[j][kk], qf[i][kk], sacc[j]);
            // sacc[j][r] = S[key=j*16+g*4+r][q=i*16+col_l] - 16, log2 domain

#pragma unroll
            for (int j = 0; j < 4; ++j) {
                bf16x4 pk;
#pragma unroll
                for (int r = 0; r < 4; ++r)
                    pk[r] = (__bf16)__builtin_amdgcn_exp2f(sacc[j][r]);
                *(bf16x4*)&lp[w][col_l * 64 +
                                 ((2 * j + (g >> 1)) ^ swz) * 8 + (g & 1) * 4] = pk;
            }

            // PV for this i (same-wave lp RAW, lgkm-ordered; vf read per i)
#pragma unroll
            for (int kk = 0; kk < 2; ++kk) {
                const int rslot = ((kk * 4 + g) ^ swz) * 8;
                bf16x8 pf = *(const bf16x8*)&lp[w][col_l * 64 + rslot];
#pragma unroll
                for (int jd = 0; jd < 4; ++jd) {
                    bf16x8 vf = *(const bf16x8*)&lv[cur][(jd * 16 + col_l) * 64 + rslot];
                    oaccT[jd][i] = MFMA16(vf, pf, oaccT[jd][i]);
                }
                csum[i] = MFMA16(ones, pf, csum[i]);
            }
        }

        // write next tile into the other buffer; one barrier per tile
        if (more) { WRITET(cur ^ 1); mcur = mnxt; }
        __syncthreads();
    }

    // epilogue: write UNNORMALIZED partial O (bf16) + f32 csum for this half
    __bf16* po = pog + (size_t)zkv * ((size_t)BATCH * NH * SEQ * DH);
    float*  co = cog + (size_t)zkv * (BATCH * NH * SEQ);
#pragma unroll
    for (int i = 0; i < 4; ++i) {
        const int s = q0 + w * 64 + i * 16 + col_l;
        if (g == 0) co[bh * SEQ + s] = csum[i][0];
#pragma unroll
        for (int jd = 0; jd < 4; ++jd) {
            bf16x4 ov;
#pragma unroll
            for (int r = 0; r < 4; ++r) ov[r] = (__bf16)oaccT[jd][i][r];
            *(bf16x4*)&po[((size_t)bh * SEQ + s) * 64 + jd * 16 + g * 4] = ov;
        }
    }
}

// ---------------------------------------------------------------------------
// Combine KV-split partials: ab = (pA + pB) / (cA + cB); (B,H,S,64)->(B,S,DM)
// ---------------------------------------------------------------------------
__global__ __launch_bounds__(256) void reduce_kernel(
    const __bf16* __restrict__ pA, const __bf16* __restrict__ pB,
    const float* __restrict__ cA, const float* __restrict__ cB,
    __bf16* __restrict__ ab)
{
    const size_t idx = ((size_t)blockIdx.x * 256 + threadIdx.x) * 8;
    const int row = (int)(idx >> 6);               // (bh,s) composite
    const float inv = 1.0f / (cA[row] + cB[row]);
    bf16x8 av = *(const bf16x8*)(pA + idx);
    bf16x8 bv = *(const bf16x8*)(pB + idx);
    bf16x8 o;
#pragma unroll
    for (int e = 0; e < 8; ++e)
        o[e] = (__bf16)(((float)av[e] + (float)bv[e]) * inv);
    const int d = (int)(idx & 63);
    const int s = (int)((idx >> 6) & 4095);
    const int h = (int)((idx >> 18) & 15);
    const int b = (int)(idx >> 22);
    *(bf16x8*)&ab[(((size_t)(b * SEQ + s)) * NH + h) * 64 + d] = o;
}

// ---------------------------------------------------------------------------
// Output projection, gload_lds staging: out = A @ Wo^T + bo (A,W bf16)
// ---------------------------------------------------------------------------
__global__ __launch_bounds__(256) void oproj_kernel(
    const __bf16* __restrict__ A, const __bf16* __restrict__ W,
    const float* __restrict__ bias, float* __restrict__ out)
{
    __shared__ __bf16 la[128 * 64];
    __shared__ __bf16 lb[128 * 64];

    const int t = threadIdx.x;
    const int lane = t & 63;
    const int w = t >> 6;
    const int wr = w >> 1, wc = w & 1;
    const int m0 = blockIdx.y * 128;
    const int n0 = blockIdx.x * 128;
    const int col_l = lane & 15;
    const int row_l = (lane >> 4) * 4;
    const int g = lane >> 4;
    const int swz = col_l & 7;

    const int lrow = lane >> 3;
    const int lchk = (lane & 7) ^ lrow;
    const __bf16* aG = A + (size_t)(m0 + w * 32 + lrow) * DM + lchk * 8;
    const __bf16* bG = W + (size_t)(n0 + w * 32 + lrow) * DM + lchk * 8;

    f32x4 acc[4][4];
#pragma unroll
    for (int i = 0; i < 4; ++i)
#pragma unroll
        for (int j = 0; j < 4; ++j) acc[i][j] = f32x4{0.f, 0.f, 0.f, 0.f};

    for (int k0 = 0; k0 < DM; k0 += 64) {
        __syncthreads();
#pragma unroll
        for (int i = 0; i < 4; ++i) {
            gload16(aG + k0 + (size_t)(i * 8) * DM, &la[(w * 32 + i * 8) * 64]);
            gload16(bG + k0 + (size_t)(i * 8) * DM, &lb[(w * 32 + i * 8) * 64]);
        }
        __syncthreads();
#pragma unroll
        for (int kk = 0; kk < 2; ++kk) {
            bf16x8 afr[4], bfr[4];
            const int rslot = ((kk * 4 + g) ^ swz) * 8;
#pragma unroll
            for (int i = 0; i < 4; ++i)
                afr[i] = *(const bf16x8*)&la[(wr * 64 + i * 16 + col_l) * 64 + rslot];
#pragma unroll
            for (int j = 0; j < 4; ++j)
                bfr[j] = *(const bf16x8*)&lb[(wc * 64 + j * 16 + col_l) * 64 + rslot];
#pragma unroll
            for (int i = 0; i < 4; ++i)
#pragma unroll
                for (int j = 0; j < 4; ++j)
                    acc[i][j] = MFMA16(afr[i], bfr[j], acc[i][j]);
        }
    }

#pragma unroll
    for (int i = 0; i < 4; ++i) {
#pragma unroll
        for (int j = 0; j < 4; ++j) {
            const int n = n0 + wc * 64 + j * 16 + col_l;
            const float bb = bias[n];
            const int mbase = m0 + wr * 64 + i * 16 + row_l;
#pragma unroll
            for (int r = 0; r < 4; ++r)
                out[(size_t)(mbase + r) * DM + n] = acc[i][j][r] + bb;
        }
    }
}

// ---------------------------------------------------------------------------
extern "C" void kernel_launch(void* const* d_in, const int* in_sizes, int n_in,
                              void* d_out, int out_size, void* d_ws, size_t ws_size,
                              hipStream_t stream) {
    (void)in_sizes; (void)n_in; (void)out_size; (void)ws_size;
    const float* Q    = (const float*)d_in[0];
    const float* K    = (const float*)d_in[1];
    const float* V    = (const float*)d_in[2];
    const float* mask = (const float*)d_in[3];
    const float* Wq   = (const float*)d_in[4];
    const float* bq   = (const float*)d_in[5];
    const float* Wk   = (const float*)d_in[6];
    const float* bk   = (const float*)d_in[7];
    const float* Wv   = (const float*)d_in[8];
    const float* bv   = (const float*)d_in[9];
    const float* Wo   = (const float*)d_in[10];
    const float* bo   = (const float*)d_in[11];
    float* out = (float*)d_out;

    const size_t NELEM = (size_t)BATCH * NH * SEQ * DH;  // 8,388,608 = 2^23
    const size_t NW    = (size_t)DM * DM;                // 1,048,576
    const size_t NBH   = (size_t)BATCH * NH * SEQ;       // 131,072
    __bf16* qb  = (__bf16*)d_ws;       // (B,H,S,64) q, pre-scaled
    __bf16* kb  = qb + NELEM;          // (B,H,S,64)
    __bf16* vtb = kb + NELEM;          // (B,H,64,S)  V pre-transposed
    __bf16* Qb  = vtb + NELEM;         // bf16 inputs; later: partial O (z=0)
    __bf16* Kb  = Qb + NELEM;          //              later: partial O (z=1)
    __bf16* Vb  = Kb + NELEM;          //              later: ab (attn out)
    __bf16* Wqb = Vb + NELEM;          // bf16 weights
    __bf16* Wkb = Wqb + NW;
    __bf16* Wvb = Wkb + NW;
    __bf16* Wob = Wvb + NW;
    float*  cs  = (float*)(Wob + NW);  // 2*NBH f32 csum partials (1 MB)
    __bf16* po  = Qb;                  // partials base (z*NELEM)
    __bf16* ab  = Vb;                  // combined attn out (B,S,DM)
    // total workspace: ~110 MiB

    cvt7_kernel<<<dim3((int)(NELEM / 8 / 256), 7), dim3(256), 0, stream>>>(
        Q, K, V, Wq, Wk, Wv, Wo, Qb, Kb, Vb, Wqb, Wkb, Wvb, Wob,
        (int)NELEM, (int)NW);
    qkv_proj_kernel<<<dim3(8, 64, 3), dim3(256), 0, stream>>>(
        Qb, Kb, Vb, Wqb, Wkb, Wvb, bq, bk, bv, qb, kb, vtb);
    attn_kernel<<<dim3(SEQ / 256, BATCH * NH, 2), dim3(256), 0, stream>>>(
        qb, kb, vtb, mask, po, cs);
    reduce_kernel<<<dim3((int)(NELEM / 8 / 256)), dim3(256), 0, stream>>>(
        po, po + NELEM, cs, cs + NBH, ab);
    oproj_kernel<<<dim3(8, 64), dim3(256), 0, stream>>>(ab, Wob, bo, out);
}

// Round 22
// 270.406 us; speedup vs baseline: 1.1456x; 1.1456x over previous
//
#include <hip/hip_runtime.h>
#include <hip/hip_bf16.h>

#define SEQ 4096
#define BATCH 2
#define NH 16
#define DH 64
#define DM 1024

typedef float f32x4 __attribute__((ext_vector_type(4)));
typedef __bf16 bf16x8 __attribute__((ext_vector_type(8)));
typedef __bf16 bf16x4 __attribute__((ext_vector_type(4)));

#define MFMA16(a, b, c) __builtin_amdgcn_mfma_f32_16x16x32_bf16((a), (b), (c), 0, 0, 0)

// Round-22: REVERT to round-18 (best measured: 267.9us total, attn 161.4).
// Rounds 19-21 (KV-split, LDS diet) all failed to raise occupancy off ~20%
// (cap is not grid/LDS/VGPR) and added overhead; abandoned.
// Config: attn = reg-staged double-buffer + fixed-max softmax (M=16 in
// mask C-init) + raw v_exp_f32 + swizzled LDS + MFMA-ones row-sum.
// GEMMs = gload_lds staging (linear LDS dest + inverse-swizzled source).

typedef const __attribute__((address_space(1))) unsigned int* gas_t;
typedef __attribute__((address_space(3))) unsigned int* las_t;
__device__ __forceinline__ void gload16(const __bf16* g, __bf16* l) {
    __builtin_amdgcn_global_load_lds((gas_t)(const void*)g, (las_t)(void*)l, 16, 0, 0);
}

// ---------------------------------------------------------------------------
// One-shot fp32 -> bf16 convert for GEMM operands (memory-bound, ~20us).
// ---------------------------------------------------------------------------
__global__ __launch_bounds__(256) void cvt7_kernel(
    const float* __restrict__ a0, const float* __restrict__ a1, const float* __restrict__ a2,
    const float* __restrict__ a3, const float* __restrict__ a4, const float* __restrict__ a5,
    const float* __restrict__ a6,
    __bf16* __restrict__ b0, __bf16* __restrict__ b1, __bf16* __restrict__ b2,
    __bf16* __restrict__ b3, __bf16* __restrict__ b4, __bf16* __restrict__ b5,
    __bf16* __restrict__ b6, int nbig, int nw)
{
    const int y = blockIdx.y;
    const float* s; __bf16* d; int n;
    switch (y) {
        case 0: s = a0; d = b0; n = nbig; break;
        case 1: s = a1; d = b1; n = nbig; break;
        case 2: s = a2; d = b2; n = nbig; break;
        case 3: s = a3; d = b3; n = nw;   break;
        case 4: s = a4; d = b4; n = nw;   break;
        case 5: s = a5; d = b5; n = nw;   break;
        default: s = a6; d = b6; n = nw;  break;
    }
    const int idx = (blockIdx.x * 256 + threadIdx.x) * 8;
    if (idx >= n) return;
    const float4 v0 = *(const float4*)(s + idx);
    const float4 v1 = *(const float4*)(s + idx + 4);
    bf16x8 o;
    o[0] = (__bf16)v0.x; o[1] = (__bf16)v0.y; o[2] = (__bf16)v0.z; o[3] = (__bf16)v0.w;
    o[4] = (__bf16)v1.x; o[5] = (__bf16)v1.y; o[6] = (__bf16)v1.z; o[7] = (__bf16)v1.w;
    *(bf16x8*)(d + idx) = o;
}

// ---------------------------------------------------------------------------
// QKV projection, bf16, gload_lds staging: C = X @ W^T + bias (NT, 128x128)
// z=0 -> q PRE-SCALED by 1/sqrt(64)*log2e; z=1 -> k; z=2 -> v^T (B,H,64,S)
// ---------------------------------------------------------------------------
__global__ __launch_bounds__(256) void qkv_proj_kernel(
    const __bf16* __restrict__ Qb, const __bf16* __restrict__ Kb, const __bf16* __restrict__ Vb,
    const __bf16* __restrict__ Wq, const __bf16* __restrict__ Wk, const __bf16* __restrict__ Wv,
    const float* __restrict__ bq, const float* __restrict__ bk, const float* __restrict__ bv,
    __bf16* __restrict__ qo, __bf16* __restrict__ ko, __bf16* __restrict__ vto)
{
    const int z = blockIdx.z;
    const __bf16* __restrict__ X    = (z == 0) ? Qb : (z == 1) ? Kb : Vb;
    const __bf16* __restrict__ W    = (z == 0) ? Wq : (z == 1) ? Wk : Wv;
    const float*  __restrict__ bias = (z == 0) ? bq : (z == 1) ? bk : bv;

    __shared__ __bf16 la[128 * 64];
    __shared__ __bf16 lb[128 * 64];

    const int t = threadIdx.x;
    const int lane = t & 63;
    const int w = t >> 6;
    const int wr = w >> 1, wc = w & 1;
    const int m0 = blockIdx.y * 128;
    const int n0 = blockIdx.x * 128;
    const int col_l = lane & 15;
    const int row_l = (lane >> 4) * 4;
    const int g = lane >> 4;
    const int swz = col_l & 7;              // read-side swizzle key (row&7)

    const int lrow = lane >> 3;             // staging: 8 lanes/row, 16B each
    const int lchk = (lane & 7) ^ lrow;     // inverse-swizzle source chunk
    const __bf16* aG = X + (size_t)(m0 + w * 32 + lrow) * DM + lchk * 8;
    const __bf16* bG = W + (size_t)(n0 + w * 32 + lrow) * DM + lchk * 8;

    f32x4 acc[4][4];
#pragma unroll
    for (int i = 0; i < 4; ++i)
#pragma unroll
        for (int j = 0; j < 4; ++j) acc[i][j] = f32x4{0.f, 0.f, 0.f, 0.f};

    for (int k0 = 0; k0 < DM; k0 += 64) {
        __syncthreads();                    // prior compute done reading la/lb
#pragma unroll
        for (int i = 0; i < 4; ++i) {
            gload16(aG + k0 + (size_t)(i * 8) * DM, &la[(w * 32 + i * 8) * 64]);
            gload16(bG + k0 + (size_t)(i * 8) * DM, &lb[(w * 32 + i * 8) * 64]);
        }
        __syncthreads();                    // vmcnt drained: tiles resident
#pragma unroll
        for (int kk = 0; kk < 2; ++kk) {
            bf16x8 afr[4], bfr[4];
            const int rslot = ((kk * 4 + g) ^ swz) * 8;
#pragma unroll
            for (int i = 0; i < 4; ++i)
                afr[i] = *(const bf16x8*)&la[(wr * 64 + i * 16 + col_l) * 64 + rslot];
#pragma unroll
            for (int j = 0; j < 4; ++j)
                bfr[j] = *(const bf16x8*)&lb[(wc * 64 + j * 16 + col_l) * 64 + rslot];
#pragma unroll
            for (int i = 0; i < 4; ++i)
#pragma unroll
                for (int j = 0; j < 4; ++j)
                    acc[i][j] = MFMA16(afr[i], bfr[j], acc[i][j]);
        }
    }

    const float qscale = (z == 0) ? 0.125f * 1.44269504f : 1.0f;

    // epilogue: C/D layout col=lane&15, row=(lane>>4)*4+reg  [m89]
#pragma unroll
    for (int i = 0; i < 4; ++i) {
#pragma unroll
        for (int j = 0; j < 4; ++j) {
            const int n = n0 + wc * 64 + j * 16 + col_l;
            const float bb = bias[n];
            const int hh = n >> 6, d = n & 63;
            const int mbase = m0 + wr * 64 + i * 16 + row_l;
            const int b = mbase >> 12;
            const int s = mbase & 4095;
            if (z == 2) {
                bf16x4 pk;
#pragma unroll
                for (int r = 0; r < 4; ++r) pk[r] = (__bf16)(acc[i][j][r] + bb);
                *(bf16x4*)&vto[((size_t)((b * NH + hh) * DH + d)) * SEQ + s] = pk;
            } else {
                __bf16* op = (z == 0) ? qo : ko;
#pragma unroll
                for (int r = 0; r < 4; ++r)
                    op[((size_t)((b * NH + hh) * SEQ + s + r)) * DH + d] =
                        (__bf16)((acc[i][j][r] + bb) * qscale);
            }
        }
    }
}

// ---------------------------------------------------------------------------
// Flash attention (round-18 best): reg-staged double-buffer + fixed-max
// softmax with RAW v_exp_f32. No setprio (measured null).
// ---------------------------------------------------------------------------
__global__ __launch_bounds__(256, 2) void attn_kernel(
    const __bf16* __restrict__ qg, const __bf16* __restrict__ kg,
    const __bf16* __restrict__ vtg, const float* __restrict__ maskg,
    __bf16* __restrict__ og)
{
    const int bh = blockIdx.y;
    const int b = bh >> 4;
    const int h = bh & 15;
    const int q0 = blockIdx.x * 256;
    const int t = threadIdx.x;
    const int lane = t & 63;
    const int w = t >> 6;
    const int col_l = lane & 15;
    const int g = lane >> 4;          // 4 lane-groups; key sub-slot g*4+r
    const int swz = col_l & 7;        // read-side swizzle key

    __shared__ __bf16 lk[2][64 * 64];
    __shared__ __bf16 lv[2][64 * 64];   // V transposed: row=d, col=key
    __shared__ __bf16 lp[4][64 * 64];   // per-wave P tile: row=q_local, col=key
    __shared__ float lm[2][64];

    const __bf16* qbase = qg + (size_t)bh * SEQ * DH;
    const __bf16* kbase = kg + (size_t)bh * SEQ * DH;
    const __bf16* vbase = vtg + (size_t)bh * DH * SEQ;

    // Q resident in registers (pre-scaled by 1/sqrt(d)*log2e)
    bf16x8 qf[4][2];
#pragma unroll
    for (int i = 0; i < 4; ++i)
#pragma unroll
        for (int kk = 0; kk < 2; ++kk)
            qf[i][kk] = *(const bf16x8*)&qbase[(size_t)(q0 + w * 64 + i * 16 + col_l) * DH +
                                              kk * 32 + g * 8];

    bf16x8 ones;
#pragma unroll
    for (int e = 0; e < 8; ++e) ones[e] = (__bf16)1.0f;

    f32x4 oaccT[4][4], csum[4];
#pragma unroll
    for (int jd = 0; jd < 4; ++jd)
#pragma unroll
        for (int i = 0; i < 4; ++i) oaccT[jd][i] = f32x4{0.f, 0.f, 0.f, 0.f};
#pragma unroll
    for (int i = 0; i < 4; ++i) csum[i] = f32x4{0.f, 0.f, 0.f, 0.f};

    const int srow = t >> 2;          // staging: 4 threads/row, 32B each
    const int wkey = srow & 7;
    const int ss0 = ((t & 3) * 2) ^ wkey;        // swizzled slot, first 16B
    const int ss1 = ((t & 3) * 2 + 1) ^ wkey;    // swizzled slot, second 16B

    // staged registers for the in-flight tile
    bf16x8 sk0, sk1, sv0, sv1;
    float smv;

    auto LOADT = [&](int j0) {
        const bf16x8* ksrc = (const bf16x8*)(kbase + (size_t)j0 * DH);
        sk0 = ksrc[t * 2];
        sk1 = ksrc[t * 2 + 1];
        const __bf16* vsrc = vbase + (size_t)srow * SEQ + j0 + (t & 3) * 16;
        sv0 = *(const bf16x8*)vsrc;
        sv1 = *(const bf16x8*)(vsrc + 8);
        smv = (t < 64) ? maskg[b * SEQ + j0 + t] : 0.0f;
    };
    auto WRITET = [&](int buf) {
        *(bf16x8*)&lk[buf][srow * 64 + ss0 * 8] = sk0;
        *(bf16x8*)&lk[buf][srow * 64 + ss1 * 8] = sk1;
        *(bf16x8*)&lv[buf][srow * 64 + ss0 * 8] = sv0;
        *(bf16x8*)&lv[buf][srow * 64 + ss1 * 8] = sv1;
        if (t < 64) lm[buf][t] = smv;
    };

    const int NT = SEQ / 64;
    LOADT(0);
    WRITET(0);
    __syncthreads();

    for (int tt = 0; tt < NT; ++tt) {
        const int cur = tt & 1;
        const bool more = (tt + 1 < NT);
        if (more) LOADT((tt + 1) * 64);   // in flight during compute

        // C-initializer: fixed max M=16 folded in (masked keys get -1e9)
        f32x4 msv[4];
#pragma unroll
        for (int j = 0; j < 4; ++j)
#pragma unroll
            for (int r = 0; r < 4; ++r)
                msv[j][r] = (lm[cur][j * 16 + g * 4 + r] == 0.0f) ? -1e9f : -16.0f;

        // K frags hoisted once per tile (A-operand: m=key block j, row=col_l)
        bf16x8 kf[4][2];
#pragma unroll
        for (int j = 0; j < 4; ++j)
#pragma unroll
            for (int kk = 0; kk < 2; ++kk)
                kf[j][kk] = *(const bf16x8*)&lk[cur][(j * 16 + col_l) * 64 +
                                                    ((kk * 4 + g) ^ swz) * 8];

        // Per q-block i: S^T = K Q^T (+(bias-16) via C-in), raw exp2, P->LDS.
#pragma unroll
        for (int i = 0; i < 4; ++i) {
            f32x4 sacc[4];
#pragma unroll
            for (int j = 0; j < 4; ++j) sacc[j] = msv[j];
#pragma unroll
            for (int kk = 0; kk < 2; ++kk)
#pragma unroll
                for (int j = 0; j < 4; ++j)
                    sacc[j] = MFMA16(kf[j][kk], qf[i][kk], sacc[j]);
            // sacc[j][r] = S[key=j*16+g*4+r][q=i*16+col_l] - 16, log2 domain

#pragma unroll
            for (int j = 0; j < 4; ++j) {
                bf16x4 pk;
#pragma unroll
                for (int r = 0; r < 4; ++r)
                    pk[r] = (__bf16)__builtin_amdgcn_exp2f(sacc[j][r]);
                *(bf16x4*)&lp[w][(i * 16 + col_l) * 64 +
                                 ((2 * j + (g >> 1)) ^ swz) * 8 + (g & 1) * 4] = pk;
            }
        }

        // O^T += V^T P^T ; row-sum rides along: csum[i] += ones * P^T
#pragma unroll
        for (int kk = 0; kk < 2; ++kk) {
            bf16x8 vf[4], pf[4];
            const int rslot = ((kk * 4 + g) ^ swz) * 8;
#pragma unroll
            for (int jd = 0; jd < 4; ++jd)
                vf[jd] = *(const bf16x8*)&lv[cur][(jd * 16 + col_l) * 64 + rslot];
#pragma unroll
            for (int i = 0; i < 4; ++i)
                pf[i] = *(const bf16x8*)&lp[w][(i * 16 + col_l) * 64 + rslot];
#pragma unroll
            for (int jd = 0; jd < 4; ++jd)
#pragma unroll
                for (int i = 0; i < 4; ++i)
                    oaccT[jd][i] = MFMA16(vf[jd], pf[i], oaccT[jd][i]);
#pragma unroll
            for (int i = 0; i < 4; ++i)
                csum[i] = MFMA16(ones, pf[i], csum[i]);
        }

        // write next tile into the other buffer; one barrier per tile
        if (more) WRITET(cur ^ 1);
        __syncthreads();
    }

    // epilogue: O /= l; lane stores 4 consecutive d (b64) per (i,jd)
#pragma unroll
    for (int i = 0; i < 4; ++i) {
        const float inv = 1.0f / csum[i][0];
        const int s = q0 + w * 64 + i * 16 + col_l;
#pragma unroll
        for (int jd = 0; jd < 4; ++jd) {
            bf16x4 ov;
#pragma unroll
            for (int r = 0; r < 4; ++r) ov[r] = (__bf16)(oaccT[jd][i][r] * inv);
            *(bf16x4*)&og[((size_t)(b * SEQ + s)) * DM + h * DH + jd * 16 + g * 4] = ov;
        }
    }
}

// ---------------------------------------------------------------------------
// Output projection, gload_lds staging: out = A @ Wo^T + bo (A,W bf16)
// ---------------------------------------------------------------------------
__global__ __launch_bounds__(256) void oproj_kernel(
    const __bf16* __restrict__ A, const __bf16* __restrict__ W,
    const float* __restrict__ bias, float* __restrict__ out)
{
    __shared__ __bf16 la[128 * 64];
    __shared__ __bf16 lb[128 * 64];

    const int t = threadIdx.x;
    const int lane = t & 63;
    const int w = t >> 6;
    const int wr = w >> 1, wc = w & 1;
    const int m0 = blockIdx.y * 128;
    const int n0 = blockIdx.x * 128;
    const int col_l = lane & 15;
    const int row_l = (lane >> 4) * 4;
    const int g = lane >> 4;
    const int swz = col_l & 7;

    const int lrow = lane >> 3;
    const int lchk = (lane & 7) ^ lrow;
    const __bf16* aG = A + (size_t)(m0 + w * 32 + lrow) * DM + lchk * 8;
    const __bf16* bG = W + (size_t)(n0 + w * 32 + lrow) * DM + lchk * 8;

    f32x4 acc[4][4];
#pragma unroll
    for (int i = 0; i < 4; ++i)
#pragma unroll
        for (int j = 0; j < 4; ++j) acc[i][j] = f32x4{0.f, 0.f, 0.f, 0.f};

    for (int k0 = 0; k0 < DM; k0 += 64) {
        __syncthreads();
#pragma unroll
        for (int i = 0; i < 4; ++i) {
            gload16(aG + k0 + (size_t)(i * 8) * DM, &la[(w * 32 + i * 8) * 64]);
            gload16(bG + k0 + (size_t)(i * 8) * DM, &lb[(w * 32 + i * 8) * 64]);
        }
        __syncthreads();
#pragma unroll
        for (int kk = 0; kk < 2; ++kk) {
            bf16x8 afr[4], bfr[4];
            const int rslot = ((kk * 4 + g) ^ swz) * 8;
#pragma unroll
            for (int i = 0; i < 4; ++i)
                afr[i] = *(const bf16x8*)&la[(wr * 64 + i * 16 + col_l) * 64 + rslot];
#pragma unroll
            for (int j = 0; j < 4; ++j)
                bfr[j] = *(const bf16x8*)&lb[(wc * 64 + j * 16 + col_l) * 64 + rslot];
#pragma unroll
            for (int i = 0; i < 4; ++i)
#pragma unroll
                for (int j = 0; j < 4; ++j)
                    acc[i][j] = MFMA16(afr[i], bfr[j], acc[i][j]);
        }
    }

#pragma unroll
    for (int i = 0; i < 4; ++i) {
#pragma unroll
        for (int j = 0; j < 4; ++j) {
            const int n = n0 + wc * 64 + j * 16 + col_l;
            const float bb = bias[n];
            const int mbase = m0 + wr * 64 + i * 16 + row_l;
#pragma unroll
            for (int r = 0; r < 4; ++r)
                out[(size_t)(mbase + r) * DM + n] = acc[i][j][r] + bb;
        }
    }
}

// ---------------------------------------------------------------------------
extern "C" void kernel_launch(void* const* d_in, const int* in_sizes, int n_in,
                              void* d_out, int out_size, void* d_ws, size_t ws_size,
                              hipStream_t stream) {
    (void)in_sizes; (void)n_in; (void)out_size; (void)ws_size;
    const float* Q    = (const float*)d_in[0];
    const float* K    = (const float*)d_in[1];
    const float* V    = (const float*)d_in[2];
    const float* mask = (const float*)d_in[3];
    const float* Wq   = (const float*)d_in[4];
    const float* bq   = (const float*)d_in[5];
    const float* Wk   = (const float*)d_in[6];
    const float* bk   = (const float*)d_in[7];
    const float* Wv   = (const float*)d_in[8];
    const float* bv   = (const float*)d_in[9];
    const float* Wo   = (const float*)d_in[10];
    const float* bo   = (const float*)d_in[11];
    float* out = (float*)d_out;

    const size_t NELEM = (size_t)BATCH * NH * SEQ * DH;  // 8,388,608
    const size_t NW    = (size_t)DM * DM;                // 1,048,576
    __bf16* qb  = (__bf16*)d_ws;       // (B,H,S,64) q, pre-scaled
    __bf16* kb  = qb + NELEM;          // (B,H,S,64)
    __bf16* vtb = kb + NELEM;          // (B,H,64,S)  V pre-transposed
    __bf16* Qb  = vtb + NELEM;         // bf16 inputs
    __bf16* Kb  = Qb + NELEM;
    __bf16* Vb  = Kb + NELEM;
    __bf16* Wqb = Vb + NELEM;          // bf16 weights
    __bf16* Wkb = Wqb + NW;
    __bf16* Wvb = Wkb + NW;
    __bf16* Wob = Wvb + NW;
    __bf16* ab  = Qb;                  // attn out aliases Qb (dead after qkv_proj)

    cvt7_kernel<<<dim3((int)(NELEM / 8 / 256), 7), dim3(256), 0, stream>>>(
        Q, K, V, Wq, Wk, Wv, Wo, Qb, Kb, Vb, Wqb, Wkb, Wvb, Wob,
        (int)NELEM, (int)NW);
    qkv_proj_kernel<<<dim3(8, 64, 3), dim3(256), 0, stream>>>(
        Qb, Kb, Vb, Wqb, Wkb, Wvb, bq, bk, bv, qb, kb, vtb);
    attn_kernel<<<dim3(SEQ / 256, BATCH * NH), dim3(256), 0, stream>>>(
        qb, kb, vtb, mask, ab);
    oproj_kernel<<<dim3(8, 64), dim3(256), 0, stream>>>(ab, Wob, bo, out);
}

// Round 24
// 268.581 us; speedup vs baseline: 1.1534x; 1.0068x over previous
//
#include <hip/hip_runtime.h>
#include <hip/hip_bf16.h>

#define SEQ 4096
#define BATCH 2
#define NH 16
#define DH 64
#define DM 1024

typedef float f32x4 __attribute__((ext_vector_type(4)));
typedef __bf16 bf16x8 __attribute__((ext_vector_type(8)));
typedef __bf16 bf16x4 __attribute__((ext_vector_type(4)));

#define MFMA16(a, b, c) __builtin_amdgcn_mfma_f32_16x16x32_bf16((a), (b), (c), 0, 0, 0)

// Round-24 (resubmit of 23): round-18/22 best config + attn mask micro-cut:
//  - lm LDS eliminated; mask held in 1 reg/lane (lane <-> key j0+lane).
//  - uniform fast path: __all(mask!=0) -> constant -16 C-init (skips
//    16 LDS reads + 16 sels per tile); shfl fallback keeps generality.
// Everything else identical to the reproduced best (270.4us):
// attn = reg-staged double-buffer + fixed-max softmax (M=16) + raw
// v_exp_f32 + swizzled LDS + MFMA-ones row-sum; GEMMs = gload_lds.

typedef const __attribute__((address_space(1))) unsigned int* gas_t;
typedef __attribute__((address_space(3))) unsigned int* las_t;
__device__ __forceinline__ void gload16(const __bf16* g, __bf16* l) {
    __builtin_amdgcn_global_load_lds((gas_t)(const void*)g, (las_t)(void*)l, 16, 0, 0);
}

// ---------------------------------------------------------------------------
// One-shot fp32 -> bf16 convert for GEMM operands (memory-bound, ~20us).
// ---------------------------------------------------------------------------
__global__ __launch_bounds__(256) void cvt7_kernel(
    const float* __restrict__ a0, const float* __restrict__ a1, const float* __restrict__ a2,
    const float* __restrict__ a3, const float* __restrict__ a4, const float* __restrict__ a5,
    const float* __restrict__ a6,
    __bf16* __restrict__ b0, __bf16* __restrict__ b1, __bf16* __restrict__ b2,
    __bf16* __restrict__ b3, __bf16* __restrict__ b4, __bf16* __restrict__ b5,
    __bf16* __restrict__ b6, int nbig, int nw)
{
    const int y = blockIdx.y;
    const float* s; __bf16* d; int n;
    switch (y) {
        case 0: s = a0; d = b0; n = nbig; break;
        case 1: s = a1; d = b1; n = nbig; break;
        case 2: s = a2; d = b2; n = nbig; break;
        case 3: s = a3; d = b3; n = nw;   break;
        case 4: s = a4; d = b4; n = nw;   break;
        case 5: s = a5; d = b5; n = nw;   break;
        default: s = a6; d = b6; n = nw;  break;
    }
    const int idx = (blockIdx.x * 256 + threadIdx.x) * 8;
    if (idx >= n) return;
    const float4 v0 = *(const float4*)(s + idx);
    const float4 v1 = *(const float4*)(s + idx + 4);
    bf16x8 o;
    o[0] = (__bf16)v0.x; o[1] = (__bf16)v0.y; o[2] = (__bf16)v0.z; o[3] = (__bf16)v0.w;
    o[4] = (__bf16)v1.x; o[5] = (__bf16)v1.y; o[6] = (__bf16)v1.z; o[7] = (__bf16)v1.w;
    *(bf16x8*)(d + idx) = o;
}

// ---------------------------------------------------------------------------
// QKV projection, bf16, gload_lds staging: C = X @ W^T + bias (NT, 128x128)
// z=0 -> q PRE-SCALED by 1/sqrt(64)*log2e; z=1 -> k; z=2 -> v^T (B,H,64,S)
// ---------------------------------------------------------------------------
__global__ __launch_bounds__(256) void qkv_proj_kernel(
    const __bf16* __restrict__ Qb, const __bf16* __restrict__ Kb, const __bf16* __restrict__ Vb,
    const __bf16* __restrict__ Wq, const __bf16* __restrict__ Wk, const __bf16* __restrict__ Wv,
    const float* __restrict__ bq, const float* __restrict__ bk, const float* __restrict__ bv,
    __bf16* __restrict__ qo, __bf16* __restrict__ ko, __bf16* __restrict__ vto)
{
    const int z = blockIdx.z;
    const __bf16* __restrict__ X    = (z == 0) ? Qb : (z == 1) ? Kb : Vb;
    const __bf16* __restrict__ W    = (z == 0) ? Wq : (z == 1) ? Wk : Wv;
    const float*  __restrict__ bias = (z == 0) ? bq : (z == 1) ? bk : bv;

    __shared__ __bf16 la[128 * 64];
    __shared__ __bf16 lb[128 * 64];

    const int t = threadIdx.x;
    const int lane = t & 63;
    const int w = t >> 6;
    const int wr = w >> 1, wc = w & 1;
    const int m0 = blockIdx.y * 128;
    const int n0 = blockIdx.x * 128;
    const int col_l = lane & 15;
    const int row_l = (lane >> 4) * 4;
    const int g = lane >> 4;
    const int swz = col_l & 7;              // read-side swizzle key (row&7)

    const int lrow = lane >> 3;             // staging: 8 lanes/row, 16B each
    const int lchk = (lane & 7) ^ lrow;     // inverse-swizzle source chunk
    const __bf16* aG = X + (size_t)(m0 + w * 32 + lrow) * DM + lchk * 8;
    const __bf16* bG = W + (size_t)(n0 + w * 32 + lrow) * DM + lchk * 8;

    f32x4 acc[4][4];
#pragma unroll
    for (int i = 0; i < 4; ++i)
#pragma unroll
        for (int j = 0; j < 4; ++j) acc[i][j] = f32x4{0.f, 0.f, 0.f, 0.f};

    for (int k0 = 0; k0 < DM; k0 += 64) {
        __syncthreads();                    // prior compute done reading la/lb
#pragma unroll
        for (int i = 0; i < 4; ++i) {
            gload16(aG + k0 + (size_t)(i * 8) * DM, &la[(w * 32 + i * 8) * 64]);
            gload16(bG + k0 + (size_t)(i * 8) * DM, &lb[(w * 32 + i * 8) * 64]);
        }
        __syncthreads();                    // vmcnt drained: tiles resident
#pragma unroll
        for (int kk = 0; kk < 2; ++kk) {
            bf16x8 afr[4], bfr[4];
            const int rslot = ((kk * 4 + g) ^ swz) * 8;
#pragma unroll
            for (int i = 0; i < 4; ++i)
                afr[i] = *(const bf16x8*)&la[(wr * 64 + i * 16 + col_l) * 64 + rslot];
#pragma unroll
            for (int j = 0; j < 4; ++j)
                bfr[j] = *(const bf16x8*)&lb[(wc * 64 + j * 16 + col_l) * 64 + rslot];
#pragma unroll
            for (int i = 0; i < 4; ++i)
#pragma unroll
                for (int j = 0; j < 4; ++j)
                    acc[i][j] = MFMA16(afr[i], bfr[j], acc[i][j]);
        }
    }

    const float qscale = (z == 0) ? 0.125f * 1.44269504f : 1.0f;

    // epilogue: C/D layout col=lane&15, row=(lane>>4)*4+reg  [m89]
#pragma unroll
    for (int i = 0; i < 4; ++i) {
#pragma unroll
        for (int j = 0; j < 4; ++j) {
            const int n = n0 + wc * 64 + j * 16 + col_l;
            const float bb = bias[n];
            const int hh = n >> 6, d = n & 63;
            const int mbase = m0 + wr * 64 + i * 16 + row_l;
            const int b = mbase >> 12;
            const int s = mbase & 4095;
            if (z == 2) {
                bf16x4 pk;
#pragma unroll
                for (int r = 0; r < 4; ++r) pk[r] = (__bf16)(acc[i][j][r] + bb);
                *(bf16x4*)&vto[((size_t)((b * NH + hh) * DH + d)) * SEQ + s] = pk;
            } else {
                __bf16* op = (z == 0) ? qo : ko;
#pragma unroll
                for (int r = 0; r < 4; ++r)
                    op[((size_t)((b * NH + hh) * SEQ + s + r)) * DH + d] =
                        (__bf16)((acc[i][j][r] + bb) * qscale);
            }
        }
    }
}

// ---------------------------------------------------------------------------
// Flash attention: reg-staged double-buffer + fixed-max softmax (raw
// v_exp_f32) + register mask with uniform fast path.
// ---------------------------------------------------------------------------
__global__ __launch_bounds__(256, 2) void attn_kernel(
    const __bf16* __restrict__ qg, const __bf16* __restrict__ kg,
    const __bf16* __restrict__ vtg, const float* __restrict__ maskg,
    __bf16* __restrict__ og)
{
    const int bh = blockIdx.y;
    const int b = bh >> 4;
    const int h = bh & 15;
    const int q0 = blockIdx.x * 256;
    const int t = threadIdx.x;
    const int lane = t & 63;
    const int w = t >> 6;
    const int col_l = lane & 15;
    const int g = lane >> 4;          // 4 lane-groups; key sub-slot g*4+r
    const int swz = col_l & 7;        // read-side swizzle key

    __shared__ __bf16 lk[2][64 * 64];
    __shared__ __bf16 lv[2][64 * 64];   // V transposed: row=d, col=key
    __shared__ __bf16 lp[4][64 * 64];   // per-wave P tile: row=q_local, col=key

    const __bf16* qbase = qg + (size_t)bh * SEQ * DH;
    const __bf16* kbase = kg + (size_t)bh * SEQ * DH;
    const __bf16* vbase = vtg + (size_t)bh * DH * SEQ;

    // Q resident in registers (pre-scaled by 1/sqrt(d)*log2e)
    bf16x8 qf[4][2];
#pragma unroll
    for (int i = 0; i < 4; ++i)
#pragma unroll
        for (int kk = 0; kk < 2; ++kk)
            qf[i][kk] = *(const bf16x8*)&qbase[(size_t)(q0 + w * 64 + i * 16 + col_l) * DH +
                                              kk * 32 + g * 8];

    bf16x8 ones;
#pragma unroll
    for (int e = 0; e < 8; ++e) ones[e] = (__bf16)1.0f;

    f32x4 oaccT[4][4], csum[4];
#pragma unroll
    for (int jd = 0; jd < 4; ++jd)
#pragma unroll
        for (int i = 0; i < 4; ++i) oaccT[jd][i] = f32x4{0.f, 0.f, 0.f, 0.f};
#pragma unroll
    for (int i = 0; i < 4; ++i) csum[i] = f32x4{0.f, 0.f, 0.f, 0.f};

    const int srow = t >> 2;          // staging: 4 threads/row, 32B each
    const int wkey = srow & 7;
    const int ss0 = ((t & 3) * 2) ^ wkey;        // swizzled slot, first 16B
    const int ss1 = ((t & 3) * 2 + 1) ^ wkey;    // swizzled slot, second 16B

    // staged registers for the in-flight tile; mask: lane <-> key j0+lane
    bf16x8 sk0, sk1, sv0, sv1;
    float mcur, mnxt;

    auto LOADT = [&](int j0) {
        const bf16x8* ksrc = (const bf16x8*)(kbase + (size_t)j0 * DH);
        sk0 = ksrc[t * 2];
        sk1 = ksrc[t * 2 + 1];
        const __bf16* vsrc = vbase + (size_t)srow * SEQ + j0 + (t & 3) * 16;
        sv0 = *(const bf16x8*)vsrc;
        sv1 = *(const bf16x8*)(vsrc + 8);
        mnxt = maskg[b * SEQ + j0 + lane];
    };
    auto WRITET = [&](int buf) {
        *(bf16x8*)&lk[buf][srow * 64 + ss0 * 8] = sk0;
        *(bf16x8*)&lk[buf][srow * 64 + ss1 * 8] = sk1;
        *(bf16x8*)&lv[buf][srow * 64 + ss0 * 8] = sv0;
        *(bf16x8*)&lv[buf][srow * 64 + ss1 * 8] = sv1;
    };

    const int NT = SEQ / 64;
    LOADT(0);
    WRITET(0);
    mcur = mnxt;
    __syncthreads();

    for (int tt = 0; tt < NT; ++tt) {
        const int cur = tt & 1;
        const bool more = (tt + 1 < NT);
        if (more) LOADT((tt + 1) * 64);   // in flight during compute

        // C-initializer: fixed max M=16 (+ -1e9 where masked).
        // Fast path: wave-uniform unmasked tile -> constant init, no shfl.
        f32x4 msv[4];
        if (__all(mcur != 0.0f)) {
#pragma unroll
            for (int j = 0; j < 4; ++j)
                msv[j] = f32x4{-16.0f, -16.0f, -16.0f, -16.0f};
        } else {
#pragma unroll
            for (int j = 0; j < 4; ++j)
#pragma unroll
                for (int r = 0; r < 4; ++r) {
                    const float mv = __shfl(mcur, j * 16 + g * 4 + r, 64);
                    msv[j][r] = (mv == 0.0f) ? -1e9f : -16.0f;
                }
        }

        // K frags hoisted once per tile (A-operand: m=key block j, row=col_l)
        bf16x8 kf[4][2];
#pragma unroll
        for (int j = 0; j < 4; ++j)
#pragma unroll
            for (int kk = 0; kk < 2; ++kk)
                kf[j][kk] = *(const bf16x8*)&lk[cur][(j * 16 + col_l) * 64 +
                                                    ((kk * 4 + g) ^ swz) * 8];

        // Per q-block i: S^T = K Q^T (+(bias-16) via C-in), raw exp2, P->LDS.
#pragma unroll
        for (int i = 0; i < 4; ++i) {
            f32x4 sacc[4];
#pragma unroll
            for (int j = 0; j < 4; ++j) sacc[j] = msv[j];
#pragma unroll
            for (int kk = 0; kk < 2; ++kk)
#pragma unroll
                for (int j = 0; j < 4; ++j)
                    sacc[j] = MFMA16(kf[j][kk], qf[i][kk], sacc[j]);
            // sacc[j][r] = S[key=j*16+g*4+r][q=i*16+col_l] - 16, log2 domain

#pragma unroll
            for (int j = 0; j < 4; ++j) {
                bf16x4 pk;
#pragma unroll
                for (int r = 0; r < 4; ++r)
                    pk[r] = (__bf16)__builtin_amdgcn_exp2f(sacc[j][r]);
                *(bf16x4*)&lp[w][(i * 16 + col_l) * 64 +
                                 ((2 * j + (g >> 1)) ^ swz) * 8 + (g & 1) * 4] = pk;
            }
        }

        // O^T += V^T P^T ; row-sum rides along: csum[i] += ones * P^T
#pragma unroll
        for (int kk = 0; kk < 2; ++kk) {
            bf16x8 vf[4], pf[4];
            const int rslot = ((kk * 4 + g) ^ swz) * 8;
#pragma unroll
            for (int jd = 0; jd < 4; ++jd)
                vf[jd] = *(const bf16x8*)&lv[cur][(jd * 16 + col_l) * 64 + rslot];
#pragma unroll
            for (int i = 0; i < 4; ++i)
                pf[i] = *(const bf16x8*)&lp[w][(i * 16 + col_l) * 64 + rslot];
#pragma unroll
            for (int jd = 0; jd < 4; ++jd)
#pragma unroll
                for (int i = 0; i < 4; ++i)
                    oaccT[jd][i] = MFMA16(vf[jd], pf[i], oaccT[jd][i]);
#pragma unroll
            for (int i = 0; i < 4; ++i)
                csum[i] = MFMA16(ones, pf[i], csum[i]);
        }

        // write next tile into the other buffer; one barrier per tile
        if (more) { WRITET(cur ^ 1); mcur = mnxt; }
        __syncthreads();
    }

    // epilogue: O /= l; lane stores 4 consecutive d (b64) per (i,jd)
#pragma unroll
    for (int i = 0; i < 4; ++i) {
        const float inv = 1.0f / csum[i][0];
        const int s = q0 + w * 64 + i * 16 + col_l;
#pragma unroll
        for (int jd = 0; jd < 4; ++jd) {
            bf16x4 ov;
#pragma unroll
            for (int r = 0; r < 4; ++r) ov[r] = (__bf16)(oaccT[jd][i][r] * inv);
            *(bf16x4*)&og[((size_t)(b * SEQ + s)) * DM + h * DH + jd * 16 + g * 4] = ov;
        }
    }
}

// ---------------------------------------------------------------------------
// Output projection, gload_lds staging: out = A @ Wo^T + bo (A,W bf16)
// ---------------------------------------------------------------------------
__global__ __launch_bounds__(256) void oproj_kernel(
    const __bf16* __restrict__ A, const __bf16* __restrict__ W,
    const float* __restrict__ bias, float* __restrict__ out)
{
    __shared__ __bf16 la[128 * 64];
    __shared__ __bf16 lb[128 * 64];

    const int t = threadIdx.x;
    const int lane = t & 63;
    const int w = t >> 6;
    const int wr = w >> 1, wc = w & 1;
    const int m0 = blockIdx.y * 128;
    const int n0 = blockIdx.x * 128;
    const int col_l = lane & 15;
    const int row_l = (lane >> 4) * 4;
    const int g = lane >> 4;
    const int swz = col_l & 7;

    const int lrow = lane >> 3;
    const int lchk = (lane & 7) ^ lrow;
    const __bf16* aG = A + (size_t)(m0 + w * 32 + lrow) * DM + lchk * 8;
    const __bf16* bG = W + (size_t)(n0 + w * 32 + lrow) * DM + lchk * 8;

    f32x4 acc[4][4];
#pragma unroll
    for (int i = 0; i < 4; ++i)
#pragma unroll
        for (int j = 0; j < 4; ++j) acc[i][j] = f32x4{0.f, 0.f, 0.f, 0.f};

    for (int k0 = 0; k0 < DM; k0 += 64) {
        __syncthreads();
#pragma unroll
        for (int i = 0; i < 4; ++i) {
            gload16(aG + k0 + (size_t)(i * 8) * DM, &la[(w * 32 + i * 8) * 64]);
            gload16(bG + k0 + (size_t)(i * 8) * DM, &lb[(w * 32 + i * 8) * 64]);
        }
        __syncthreads();
#pragma unroll
        for (int kk = 0; kk < 2; ++kk) {
            bf16x8 afr[4], bfr[4];
            const int rslot = ((kk * 4 + g) ^ swz) * 8;
#pragma unroll
            for (int i = 0; i < 4; ++i)
                afr[i] = *(const bf16x8*)&la[(wr * 64 + i * 16 + col_l) * 64 + rslot];
#pragma unroll
            for (int j = 0; j < 4; ++j)
                bfr[j] = *(const bf16x8*)&lb[(wc * 64 + j * 16 + col_l) * 64 + rslot];
#pragma unroll
            for (int i = 0; i < 4; ++i)
#pragma unroll
                for (int j = 0; j < 4; ++j)
                    acc[i][j] = MFMA16(afr[i], bfr[j], acc[i][j]);
        }
    }

#pragma unroll
    for (int i = 0; i < 4; ++i) {
#pragma unroll
        for (int j = 0; j < 4; ++j) {
            const int n = n0 + wc * 64 + j * 16 + col_l;
            const float bb = bias[n];
            const int mbase = m0 + wr * 64 + i * 16 + row_l;
#pragma unroll
            for (int r = 0; r < 4; ++r)
                out[(size_t)(mbase + r) * DM + n] = acc[i][j][r] + bb;
        }
    }
}

// ---------------------------------------------------------------------------
extern "C" void kernel_launch(void* const* d_in, const int* in_sizes, int n_in,
                              void* d_out, int out_size, void* d_ws, size_t ws_size,
                              hipStream_t stream) {
    (void)in_sizes; (void)n_in; (void)out_size; (void)ws_size;
    const float* Q    = (const float*)d_in[0];
    const float* K    = (const float*)d_in[1];
    const float* V    = (const float*)d_in[2];
    const float* mask = (const float*)d_in[3];
    const float* Wq   = (const float*)d_in[4];
    const float* bq   = (const float*)d_in[5];
    const float* Wk   = (const float*)d_in[6];
    const float* bk   = (const float*)d_in[7];
    const float* Wv   = (const float*)d_in[8];
    const float* bv   = (const float*)d_in[9];
    const float* Wo   = (const float*)d_in[10];
    const float* bo   = (const float*)d_in[11];
    float* out = (float*)d_out;

    const size_t NELEM = (size_t)BATCH * NH * SEQ * DH;  // 8,388,608
    const size_t NW    = (size_t)DM * DM;                // 1,048,576
    __bf16* qb  = (__bf16*)d_ws;       // (B,H,S,64) q, pre-scaled
    __bf16* kb  = qb + NELEM;          // (B,H,S,64)
    __bf16* vtb = kb + NELEM;          // (B,H,64,S)  V pre-transposed
    __bf16* Qb  = vtb + NELEM;         // bf16 inputs
    __bf16* Kb  = Qb + NELEM;
    __bf16* Vb  = Kb + NELEM;
    __bf16* Wqb = Vb + NELEM;          // bf16 weights
    __bf16* Wkb = Wqb + NW;
    __bf16* Wvb = Wkb + NW;
    __bf16* Wob = Wvb + NW;
    __bf16* ab  = Qb;                  // attn out aliases Qb (dead after qkv_proj)

    cvt7_kernel<<<dim3((int)(NELEM / 8 / 256), 7), dim3(256), 0, stream>>>(
        Q, K, V, Wq, Wk, Wv, Wo, Qb, Kb, Vb, Wqb, Wkb, Wvb, Wob,
        (int)NELEM, (int)NW);
    qkv_proj_kernel<<<dim3(8, 64, 3), dim3(256), 0, stream>>>(
        Qb, Kb, Vb, Wqb, Wkb, Wvb, bq, bk, bv, qb, kb, vtb);
    attn_kernel<<<dim3(SEQ / 256, BATCH * NH), dim3(256), 0, stream>>>(
        qb, kb, vtb, mask, ab);
    oproj_kernel<<<dim3(8, 64), dim3(256), 0, stream>>>(ab, Wob, bo, out);
}